// Round 1
// baseline (973.167 us; speedup 1.0000x reference)
//
#include <hip/hip_runtime.h>
#include <math.h>

// ---------------- CSR build ----------------

__global__ __launch_bounds__(256) void k_hist(const int* __restrict__ dst, int* __restrict__ deg, int E){
  int i = blockIdx.x*blockDim.x + threadIdx.x;
  if (i < E) atomicAdd(&deg[dst[i]], 1);
}

__global__ __launch_bounds__(256) void k_scanA(const int* __restrict__ deg, int* __restrict__ partials, int N){
  int base = blockIdx.x*1024;
  int t = threadIdx.x;
  int s = 0;
  for (int j=t; j<1024; j+=256){ int idx=base+j; if (idx<N) s += deg[idx]; }
  for (int off=32; off; off>>=1) s += __shfl_down(s, off);
  __shared__ int red[4];
  int wid=t>>6, lane=t&63;
  if (lane==0) red[wid]=s;
  __syncthreads();
  if (t==0) partials[blockIdx.x] = red[0]+red[1]+red[2]+red[3];
}

// single block of 128 threads; nb <= 128
__global__ __launch_bounds__(128) void k_scanB(int* partials, int nb, int* row_ptr, int N){
  __shared__ int lds[128];
  int t = threadIdx.x;
  int v = (t<nb)? partials[t] : 0;
  lds[t]=v; __syncthreads();
  int x=v;
  for (int off=1; off<128; off<<=1){
    int y = (t>=off)? lds[t-off] : 0;
    __syncthreads();
    x += y; lds[t]=x;
    __syncthreads();
  }
  if (t<nb) partials[t] = x - v;   // exclusive scan in place
  if (t==127) row_ptr[N] = x;      // total = E
}

__global__ __launch_bounds__(1024) void k_scanC(const int* __restrict__ deg, const int* __restrict__ partials,
                        int* __restrict__ row_ptr, int* __restrict__ cursor, int N){
  __shared__ int lds[1024];
  int base = blockIdx.x*1024;
  int t = threadIdx.x;
  int idx = base+t;
  int v = (idx<N)? deg[idx] : 0;
  lds[t]=v; __syncthreads();
  int x=v;
  for (int off=1; off<1024; off<<=1){
    int y = (t>=off)? lds[t-off] : 0;
    __syncthreads();
    x += y; lds[t]=x;
    __syncthreads();
  }
  if (idx<N){
    int out = partials[blockIdx.x] + x - v;
    row_ptr[idx]=out; cursor[idx]=out;
  }
}

__global__ __launch_bounds__(256) void k_scatter(const int* __restrict__ src, const int* __restrict__ dst,
                          int* __restrict__ cursor, int* __restrict__ csr_src, int E){
  int i = blockIdx.x*blockDim.x + threadIdx.x;
  if (i<E){
    int pos = atomicAdd(&cursor[dst[i]], 1);
    csr_src[pos] = src[i];
  }
}

// ---------------- GEMM: [N,128] x [128,128] -> [N,128] ----------------
// 64-row tile per block; 256 threads; thread computes 8 rows x 4 cols.
__global__ __launch_bounds__(256) void k_gemm128(const float* __restrict__ A, const float* __restrict__ W,
                                                 float* __restrict__ F, int N){
  __shared__ float hs[32][68];   // hs[k][row] (transposed chunk), stride 68 keeps float4 16B-aligned
  __shared__ float ws[32][128];  // ws[k][col]
  int t = threadIdx.x;
  int rowBase = blockIdx.x*64;
  int rg8 = (t>>5)*8;          // row sub-block base (0..56)
  int cq  = (t&31)*4;          // col quad base (0..124)
  float acc[8][4] = {};
  for (int kc=0; kc<128; kc+=32){
    { // stage h chunk transposed: thread reads row=t>>2, k-offsets (t&3)*8 .. +7
      int row = t>>2; int kk = (t&3)*8;
      int grow = rowBase+row;
      float4 v0, v1;
      if (grow < N){
        v0 = *(const float4*)&A[(size_t)grow*128 + kc + kk];
        v1 = *(const float4*)&A[(size_t)grow*128 + kc + kk + 4];
      } else { v0 = make_float4(0,0,0,0); v1 = v0; }
      hs[kk+0][row]=v0.x; hs[kk+1][row]=v0.y; hs[kk+2][row]=v0.z; hs[kk+3][row]=v0.w;
      hs[kk+4][row]=v1.x; hs[kk+5][row]=v1.y; hs[kk+6][row]=v1.z; hs[kk+7][row]=v1.w;
    }
    { // stage W chunk: thread t: k=t>>3, cols (t&7)*16 .. +15
      int k = t>>3; int c0 = (t&7)*16;
      const float4* wp = (const float4*)&W[(size_t)(kc+k)*128 + c0];
      float4 w0=wp[0], w1=wp[1], w2=wp[2], w3=wp[3];
      *(float4*)&ws[k][c0+ 0]=w0; *(float4*)&ws[k][c0+ 4]=w1;
      *(float4*)&ws[k][c0+ 8]=w2; *(float4*)&ws[k][c0+12]=w3;
    }
    __syncthreads();
    #pragma unroll
    for (int k=0;k<32;k++){
      float4 bv  = *(const float4*)&ws[k][cq];
      float4 av0 = *(const float4*)&hs[k][rg8];
      float4 av1 = *(const float4*)&hs[k][rg8+4];
      float a8[8] = {av0.x,av0.y,av0.z,av0.w,av1.x,av1.y,av1.z,av1.w};
      float b4[4] = {bv.x,bv.y,bv.z,bv.w};
      #pragma unroll
      for (int r=0;r<8;r++)
        #pragma unroll
        for (int c=0;c<4;c++)
          acc[r][c] = fmaf(a8[r], b4[c], acc[r][c]);
    }
    __syncthreads();
  }
  int rowTop = rowBase + rg8;
  #pragma unroll
  for (int r=0;r<8;r++){
    int row = rowTop + r;
    if (row < N){
      float4 v = make_float4(acc[r][0],acc[r][1],acc[r][2],acc[r][3]);
      *(float4*)&F[(size_t)row*128 + cq] = v;
    }
  }
}

// ---------------- el/er for H=4, D=32 ----------------
// one wave per node: lane l -> head l/16, elements 2*(l%16), +1
__global__ __launch_bounds__(256) void k_eler(const float* __restrict__ F, const float* __restrict__ al,
                                              const float* __restrict__ ar, float* __restrict__ el,
                                              float* __restrict__ er, int N){
  int node = (blockIdx.x*blockDim.x + threadIdx.x)>>6;
  int lane = threadIdx.x & 63;
  if (node >= N) return;
  int h = lane>>4;
  int d2 = (lane&15)*2;
  float2 f  = *(const float2*)&F[(size_t)node*128 + h*32 + d2];
  float2 aL = *(const float2*)&al[h*32 + d2];
  float2 aR = *(const float2*)&ar[h*32 + d2];
  float pl = f.x*aL.x + f.y*aL.y;
  float pr = f.x*aR.x + f.y*aR.y;
  for (int off=8; off; off>>=1){ pl += __shfl_xor(pl, off); pr += __shfl_xor(pr, off); }
  if ((lane&15)==0){ el[node*4+h]=pl; er[node*4+h]=pr; }
}

// ---------------- fused edge-softmax + aggregation (H=4,D=32) ----------------
// one wave per dst node; lane l owns elements 2l,2l+1 (head l/16); no atomics.
__global__ __launch_bounds__(256) void k_agg128(const float* __restrict__ F, const float* __restrict__ el,
                         const float* __restrict__ er, const int* __restrict__ row_ptr,
                         const int* __restrict__ csr_src, float* __restrict__ out, int N){
  int node = (blockIdx.x*blockDim.x + threadIdx.x)>>6;
  int lane = threadIdx.x & 63;
  if (node >= N) return;
  int h = lane>>4;
  float erv = er[node*4+h];
  int beg = row_ptr[node], end = row_ptr[node+1];
  float acc0=0.f, acc1=0.f, denom=0.f;
  for (int e=beg; e<end; e++){
    int s = csr_src[e];
    float ev = el[s*4+h] + erv;
    ev = ev>0.f ? ev : 0.2f*ev;              // leaky_relu
    float ee = __expf(ev);                   // softmax without max-shift (safe range)
    denom += ee;
    float2 f = *(const float2*)&F[(size_t)s*128 + lane*2];
    acc0 = fmaf(ee, f.x, acc0);
    acc1 = fmaf(ee, f.y, acc1);
  }
  float inv = 1.0f/denom;
  float o0 = acc0*inv, o1 = acc1*inv;
  o0 = o0>0.f ? o0 : expm1f(o0);             // elu
  o1 = o1>0.f ? o1 : expm1f(o1);
  *(float2*)&out[(size_t)node*128 + lane*2] = make_float2(o0,o1);
}

// ---------------- layer-2 GEMM [N,128]x[128,40] fused with el2/er2 ----------------
// one wave per row; lane l (<40) computes column l.
__global__ __launch_bounds__(256) void k_gemm40(const float* __restrict__ A, const float* __restrict__ W,
                        const float* __restrict__ al, const float* __restrict__ ar,
                        float* __restrict__ F, float* __restrict__ el, float* __restrict__ er, int N){
  __shared__ float ws[5120];     // W2 [128][40]
  __shared__ float sal[64], sar[64];
  int t = threadIdx.x;
  for (int i=t; i<5120; i+=256) ws[i] = W[i];
  if (t<40){ sal[t]=al[t]; sar[t]=ar[t]; }
  else if (t<64){ sal[t]=0.f; sar[t]=0.f; }
  __syncthreads();
  int node = blockIdx.x*4 + (t>>6);
  int lane = t & 63;
  if (node >= N) return;
  int l40 = lane<40 ? lane : 0;
  const float* a = A + (size_t)node*128;
  float acc = 0.f;
  #pragma unroll
  for (int k=0;k<128;k+=4){
    float4 hv = *(const float4*)&a[k];
    acc = fmaf(hv.x, ws[(k+0)*40+l40], acc);
    acc = fmaf(hv.y, ws[(k+1)*40+l40], acc);
    acc = fmaf(hv.z, ws[(k+2)*40+l40], acc);
    acc = fmaf(hv.w, ws[(k+3)*40+l40], acc);
  }
  bool act = lane<40;
  float pl = act ? acc*sal[lane] : 0.f;
  float pr = act ? acc*sar[lane] : 0.f;
  for (int off=32; off; off>>=1){ pl += __shfl_xor(pl, off); pr += __shfl_xor(pr, off); }
  if (lane==0){ el[node]=pl; er[node]=pr; }
  if (act) F[(size_t)node*40 + lane] = acc;
}

// ---------------- final aggregation (H=1,D=40) + log_softmax ----------------
__global__ __launch_bounds__(256) void k_agg40(const float* __restrict__ F, const float* __restrict__ el,
                       const float* __restrict__ er, const int* __restrict__ row_ptr,
                       const int* __restrict__ csr_src, float* __restrict__ out, int N){
  int node = (blockIdx.x*blockDim.x + threadIdx.x)>>6;
  int lane = threadIdx.x & 63;
  if (node >= N) return;
  bool act = lane<40;
  int l40 = act ? lane : 0;
  float erv = er[node];
  int beg = row_ptr[node], end = row_ptr[node+1];
  float acc=0.f, denom=0.f;
  for (int e=beg; e<end; e++){
    int s = csr_src[e];
    float ev = el[s] + erv;
    ev = ev>0.f ? ev : 0.2f*ev;
    float ee = __expf(ev);
    denom += ee;
    float f = F[(size_t)s*40 + l40];
    acc = fmaf(ee, f, acc);
  }
  float logit = acc/denom;
  float m = act ? logit : -INFINITY;
  for (int off=32; off; off>>=1) m = fmaxf(m, __shfl_xor(m, off));
  float ex = act ? expf(logit - m) : 0.f;
  float ssum = ex;
  for (int off=32; off; off>>=1) ssum += __shfl_xor(ssum, off);
  if (act) out[(size_t)node*40 + lane] = logit - m - logf(ssum);
}

extern "C" void kernel_launch(void* const* d_in, const int* in_sizes, int n_in,
                              void* d_out, int out_size, void* d_ws, size_t ws_size,
                              hipStream_t stream){
  const float* inputs = (const float*)d_in[0];
  const float* W0  = (const float*)d_in[1];
  const float* al0 = (const float*)d_in[2];
  const float* ar0 = (const float*)d_in[3];
  const float* W1  = (const float*)d_in[4];
  const float* al1 = (const float*)d_in[5];
  const float* ar1 = (const float*)d_in[6];
  const float* W2  = (const float*)d_in[7];
  const float* al2 = (const float*)d_in[8];
  const float* ar2 = (const float*)d_in[9];
  const int* src = (const int*)d_in[10];
  const int* dst = (const int*)d_in[11];
  int N = in_sizes[0]/128;
  int E = in_sizes[10];

  char* p = (char*)d_ws;
  auto carve = [&](size_t bytes)->char*{ char* q=p; p += ((bytes+255)/256)*256; return q; };
  float* bufFeat = (float*)carve((size_t)N*128*4);
  float* bufH    = (float*)carve((size_t)N*128*4);
  float* el  = (float*)carve((size_t)N*4*4);
  float* er  = (float*)carve((size_t)N*4*4);
  float* el2 = (float*)carve((size_t)N*4);
  float* er2 = (float*)carve((size_t)N*4);
  int* deg     = (int*)carve((size_t)N*4);
  int* row_ptr = (int*)carve((size_t)(N+1)*4);
  int* cursor  = (int*)carve((size_t)N*4);
  int* partials= (int*)carve(128*4);
  int* csr_src = (int*)carve((size_t)E*4);

  hipMemsetAsync(deg, 0, (size_t)N*4, stream);
  int nchunk = (N+1023)/1024;
  k_hist   <<<(E+255)/256, 256, 0, stream>>>(dst, deg, E);
  k_scanA  <<<nchunk, 256, 0, stream>>>(deg, partials, N);
  k_scanB  <<<1, 128, 0, stream>>>(partials, nchunk, row_ptr, N);
  k_scanC  <<<nchunk, 1024, 0, stream>>>(deg, partials, row_ptr, cursor, N);
  k_scatter<<<(E+255)/256, 256, 0, stream>>>(src, dst, cursor, csr_src, E);

  int gRows = (N+63)/64;
  int gWave = (N+3)/4;
  // layer 0
  k_gemm128<<<gRows,256,0,stream>>>(inputs, W0, bufFeat, N);
  k_eler   <<<gWave,256,0,stream>>>(bufFeat, al0, ar0, el, er, N);
  k_agg128 <<<gWave,256,0,stream>>>(bufFeat, el, er, row_ptr, csr_src, bufH, N);
  // layer 1
  k_gemm128<<<gRows,256,0,stream>>>(bufH, W1, bufFeat, N);
  k_eler   <<<gWave,256,0,stream>>>(bufFeat, al1, ar1, el, er, N);
  k_agg128 <<<gWave,256,0,stream>>>(bufFeat, el, er, row_ptr, csr_src, bufH, N);
  // layer 2
  k_gemm40 <<<gWave,256,0,stream>>>(bufH, W2, al2, ar2, bufFeat, el2, er2, N);
  k_agg40  <<<gWave,256,0,stream>>>(bufFeat, el2, er2, row_ptr, csr_src, (float*)d_out, N);
}

// Round 2
// 651.287 us; speedup vs baseline: 1.4942x; 1.4942x over previous
//
#include <hip/hip_runtime.h>
#include <math.h>

typedef unsigned int uint32;

__device__ inline uint32 bf16rn(float x){            // fp32 -> bf16 (RNE), in low 16 bits
  uint32 b = __float_as_uint(x);
  return (b + 0x7fffu + ((b>>16)&1u)) >> 16;
}
__device__ inline float bf16lo(uint32 v){ return __uint_as_float(v<<16); }
__device__ inline float bf16hi(uint32 v){ return __uint_as_float(v & 0xffff0000u); }

// ---------------- CSR build ----------------

__global__ __launch_bounds__(256) void k_hist(const int* __restrict__ dst, int* __restrict__ deg, int E){
  int i = blockIdx.x*blockDim.x + threadIdx.x;
  if (i < E) atomicAdd(&deg[dst[i]], 1);
}

__global__ __launch_bounds__(256) void k_scanA(const int* __restrict__ deg, int* __restrict__ partials, int N){
  int base = blockIdx.x*1024;
  int t = threadIdx.x;
  int s = 0;
  for (int j=t; j<1024; j+=256){ int idx=base+j; if (idx<N) s += deg[idx]; }
  for (int off=32; off; off>>=1) s += __shfl_down(s, off);
  __shared__ int red[4];
  int wid=t>>6, lane=t&63;
  if (lane==0) red[wid]=s;
  __syncthreads();
  if (t==0) partials[blockIdx.x] = red[0]+red[1]+red[2]+red[3];
}

__global__ __launch_bounds__(128) void k_scanB(int* partials, int nb, int* row_ptr, int N){
  __shared__ int lds[128];
  int t = threadIdx.x;
  int v = (t<nb)? partials[t] : 0;
  lds[t]=v; __syncthreads();
  int x=v;
  for (int off=1; off<128; off<<=1){
    int y = (t>=off)? lds[t-off] : 0;
    __syncthreads();
    x += y; lds[t]=x;
    __syncthreads();
  }
  if (t<nb) partials[t] = x - v;
  if (t==127) row_ptr[N] = x;
}

__global__ __launch_bounds__(1024) void k_scanC(const int* __restrict__ deg, const int* __restrict__ partials,
                        int* __restrict__ row_ptr, int* __restrict__ cursor, int N){
  __shared__ int lds[1024];
  int base = blockIdx.x*1024;
  int t = threadIdx.x;
  int idx = base+t;
  int v = (idx<N)? deg[idx] : 0;
  lds[t]=v; __syncthreads();
  int x=v;
  for (int off=1; off<1024; off<<=1){
    int y = (t>=off)? lds[t-off] : 0;
    __syncthreads();
    x += y; lds[t]=x;
    __syncthreads();
  }
  if (idx<N){
    int out = partials[blockIdx.x] + x - v;
    row_ptr[idx]=out; cursor[idx]=out;
  }
}

__global__ __launch_bounds__(256) void k_scatter(const int* __restrict__ src, const int* __restrict__ dst,
                          int* __restrict__ cursor, int* __restrict__ csr_src, int E){
  int i = blockIdx.x*blockDim.x + threadIdx.x;
  if (i<E){
    int pos = atomicAdd(&cursor[dst[i]], 1);
    csr_src[pos] = src[i];
  }
}

// ---------------- GEMM [N,128]x[128,128] -> bf16 F + fused el/er ----------------
// 64-row tile per block; 256 threads; thread computes 8 rows x 4 cols.
__global__ __launch_bounds__(256) void k_gemm128(const float* __restrict__ A, const float* __restrict__ W,
                                                 const float* __restrict__ al, const float* __restrict__ ar,
                                                 unsigned short* __restrict__ Fb,
                                                 float* __restrict__ el, float* __restrict__ er, int N){
  __shared__ float hs[32][68];
  __shared__ float ws[32][128];
  int t = threadIdx.x;
  int rowBase = blockIdx.x*64;
  int rg8 = (t>>5)*8;
  int cq  = (t&31)*4;
  float acc[8][4] = {};
  for (int kc=0; kc<128; kc+=32){
    {
      int row = t>>2; int kk = (t&3)*8;
      int grow = rowBase+row;
      float4 v0, v1;
      if (grow < N){
        v0 = *(const float4*)&A[(size_t)grow*128 + kc + kk];
        v1 = *(const float4*)&A[(size_t)grow*128 + kc + kk + 4];
      } else { v0 = make_float4(0,0,0,0); v1 = v0; }
      hs[kk+0][row]=v0.x; hs[kk+1][row]=v0.y; hs[kk+2][row]=v0.z; hs[kk+3][row]=v0.w;
      hs[kk+4][row]=v1.x; hs[kk+5][row]=v1.y; hs[kk+6][row]=v1.z; hs[kk+7][row]=v1.w;
    }
    {
      int k = t>>3; int c0 = (t&7)*16;
      const float4* wp = (const float4*)&W[(size_t)(kc+k)*128 + c0];
      float4 w0=wp[0], w1=wp[1], w2=wp[2], w3=wp[3];
      *(float4*)&ws[k][c0+ 0]=w0; *(float4*)&ws[k][c0+ 4]=w1;
      *(float4*)&ws[k][c0+ 8]=w2; *(float4*)&ws[k][c0+12]=w3;
    }
    __syncthreads();
    #pragma unroll
    for (int k=0;k<32;k++){
      float4 bv  = *(const float4*)&ws[k][cq];
      float4 av0 = *(const float4*)&hs[k][rg8];
      float4 av1 = *(const float4*)&hs[k][rg8+4];
      float a8[8] = {av0.x,av0.y,av0.z,av0.w,av1.x,av1.y,av1.z,av1.w};
      float b4[4] = {bv.x,bv.y,bv.z,bv.w};
      #pragma unroll
      for (int r=0;r<8;r++)
        #pragma unroll
        for (int c=0;c<4;c++)
          acc[r][c] = fmaf(a8[r], b4[c], acc[r][c]);
    }
    __syncthreads();
  }
  // epilogue: bf16 store + fused el/er
  float al4[4], ar4[4];
  #pragma unroll
  for (int i=0;i<4;i++){ al4[i]=al[cq+i]; ar4[i]=ar[cq+i]; }
  int c = t&31;
  int h = c>>3;                       // head = cq/32
  int rowTop = rowBase + rg8;
  #pragma unroll
  for (int r=0;r<8;r++){
    int row = rowTop + r;
    if (row < N){
      uint32 u0 = bf16rn(acc[r][0]) | (bf16rn(acc[r][1])<<16);
      uint32 u1 = bf16rn(acc[r][2]) | (bf16rn(acc[r][3])<<16);
      *(uint2*)(Fb + (size_t)row*128 + cq) = make_uint2(u0,u1);
    }
    float pl = acc[r][0]*al4[0]+acc[r][1]*al4[1]+acc[r][2]*al4[2]+acc[r][3]*al4[3];
    float pr = acc[r][0]*ar4[0]+acc[r][1]*ar4[1]+acc[r][2]*ar4[2]+acc[r][3]*ar4[3];
    pl += __shfl_xor(pl,1); pr += __shfl_xor(pr,1);
    pl += __shfl_xor(pl,2); pr += __shfl_xor(pr,2);
    pl += __shfl_xor(pl,4); pr += __shfl_xor(pr,4);
    if ((c&7)==0 && row < N){ el[(size_t)row*4+h]=pl; er[(size_t)row*4+h]=pr; }
  }
}

// ---------------- fused edge-softmax + aggregation (H=4,D=32), bf16 gather ----------------
// one wave per dst node; lane l owns elements 2l,2l+1 (head l/16); edge list in registers.
__global__ __launch_bounds__(256) void k_agg128(const uint32* __restrict__ Fu, const float* __restrict__ el,
                         const float* __restrict__ er, const int* __restrict__ row_ptr,
                         const int* __restrict__ csr_src, float* __restrict__ out, int N){
  int node = (blockIdx.x*blockDim.x + threadIdx.x)>>6;
  int lane = threadIdx.x & 63;
  if (node >= N) return;
  int h = lane>>4;
  float erv = er[(size_t)node*4+h];
  int beg = row_ptr[node], end = row_ptr[node+1];
  int deg = end - beg;
  int sv = (beg + lane < end) ? csr_src[beg+lane] : 0;   // edge list in registers (deg<=64)
  float acc0=0.f, acc1=0.f, denom=0.f;
  int nmain = deg > 64 ? 64 : deg;
  int i = 0;
  for (; i+4 <= nmain; i+=4){
    int s0=__shfl(sv,i+0), s1=__shfl(sv,i+1), s2=__shfl(sv,i+2), s3=__shfl(sv,i+3);
    float e0=el[(size_t)s0*4+h], e1=el[(size_t)s1*4+h], e2=el[(size_t)s2*4+h], e3=el[(size_t)s3*4+h];
    uint32 v0=Fu[(size_t)s0*64+lane], v1=Fu[(size_t)s1*64+lane];
    uint32 v2=Fu[(size_t)s2*64+lane], v3=Fu[(size_t)s3*64+lane];
    float x;
    x=e0+erv; x=x>0.f?x:0.2f*x; x=__expf(x); denom+=x; acc0=fmaf(x,bf16lo(v0),acc0); acc1=fmaf(x,bf16hi(v0),acc1);
    x=e1+erv; x=x>0.f?x:0.2f*x; x=__expf(x); denom+=x; acc0=fmaf(x,bf16lo(v1),acc0); acc1=fmaf(x,bf16hi(v1),acc1);
    x=e2+erv; x=x>0.f?x:0.2f*x; x=__expf(x); denom+=x; acc0=fmaf(x,bf16lo(v2),acc0); acc1=fmaf(x,bf16hi(v2),acc1);
    x=e3+erv; x=x>0.f?x:0.2f*x; x=__expf(x); denom+=x; acc0=fmaf(x,bf16lo(v3),acc0); acc1=fmaf(x,bf16hi(v3),acc1);
  }
  for (; i<nmain; i++){
    int s=__shfl(sv,i);
    float x=el[(size_t)s*4+h]+erv; x=x>0.f?x:0.2f*x; x=__expf(x);
    uint32 v=Fu[(size_t)s*64+lane];
    denom+=x; acc0=fmaf(x,bf16lo(v),acc0); acc1=fmaf(x,bf16hi(v),acc1);
  }
  if (deg > 64){
    for (int e=beg+64; e<end; e++){
      int s=csr_src[e];
      float x=el[(size_t)s*4+h]+erv; x=x>0.f?x:0.2f*x; x=__expf(x);
      uint32 v=Fu[(size_t)s*64+lane];
      denom+=x; acc0=fmaf(x,bf16lo(v),acc0); acc1=fmaf(x,bf16hi(v),acc1);
    }
  }
  float inv = 1.0f/denom;
  float o0 = acc0*inv, o1 = acc1*inv;
  o0 = o0>0.f ? o0 : expm1f(o0);
  o1 = o1>0.f ? o1 : expm1f(o1);
  *(float2*)&out[(size_t)node*128 + lane*2] = make_float2(o0,o1);
}

// ---------------- layer-2 GEMM [N,128]x[128,40] fused with el2/er2, bf16 F ----------------
__global__ __launch_bounds__(256) void k_gemm40(const float* __restrict__ A, const float* __restrict__ W,
                        const float* __restrict__ al, const float* __restrict__ ar,
                        unsigned short* __restrict__ Fb, float* __restrict__ el, float* __restrict__ er, int N){
  __shared__ float ws[5120];
  __shared__ float sal[64], sar[64];
  int t = threadIdx.x;
  for (int i=t; i<5120; i+=256) ws[i] = W[i];
  if (t<40){ sal[t]=al[t]; sar[t]=ar[t]; }
  else if (t<64){ sal[t]=0.f; sar[t]=0.f; }
  __syncthreads();
  int node = blockIdx.x*4 + (t>>6);
  int lane = t & 63;
  if (node >= N) return;
  int l40 = lane<40 ? lane : 0;
  const float* a = A + (size_t)node*128;
  float acc = 0.f;
  #pragma unroll
  for (int k=0;k<128;k+=4){
    float4 hv = *(const float4*)&a[k];
    acc = fmaf(hv.x, ws[(k+0)*40+l40], acc);
    acc = fmaf(hv.y, ws[(k+1)*40+l40], acc);
    acc = fmaf(hv.z, ws[(k+2)*40+l40], acc);
    acc = fmaf(hv.w, ws[(k+3)*40+l40], acc);
  }
  bool act = lane<40;
  float pl = act ? acc*sal[lane] : 0.f;
  float pr = act ? acc*sar[lane] : 0.f;
  for (int off=32; off; off>>=1){ pl += __shfl_xor(pl, off); pr += __shfl_xor(pr, off); }
  if (lane==0){ el[node]=pl; er[node]=pr; }
  if (act) Fb[(size_t)node*40 + lane] = (unsigned short)bf16rn(acc);
}

// ---------------- final aggregation (H=1,D=40) + log_softmax, bf16 gather ----------------
__global__ __launch_bounds__(256) void k_agg40(const unsigned short* __restrict__ Fb, const float* __restrict__ el,
                       const float* __restrict__ er, const int* __restrict__ row_ptr,
                       const int* __restrict__ csr_src, float* __restrict__ out, int N){
  int node = (blockIdx.x*blockDim.x + threadIdx.x)>>6;
  int lane = threadIdx.x & 63;
  if (node >= N) return;
  bool act = lane<40;
  int l40 = act ? lane : 0;
  float erv = er[node];
  int beg = row_ptr[node], end = row_ptr[node+1];
  int deg = end - beg;
  int sv = (beg + lane < end) ? csr_src[beg+lane] : 0;
  float acc=0.f, denom=0.f;
  int nmain = deg > 64 ? 64 : deg;
  int i = 0;
  for (; i+2 <= nmain; i+=2){
    int s0=__shfl(sv,i+0), s1=__shfl(sv,i+1);
    float e0=el[s0], e1=el[s1];
    unsigned short f0=Fb[(size_t)s0*40+l40], f1=Fb[(size_t)s1*40+l40];
    float x;
    x=e0+erv; x=x>0.f?x:0.2f*x; x=__expf(x); denom+=x; acc=fmaf(x,__uint_as_float(((uint32)f0)<<16),acc);
    x=e1+erv; x=x>0.f?x:0.2f*x; x=__expf(x); denom+=x; acc=fmaf(x,__uint_as_float(((uint32)f1)<<16),acc);
  }
  for (; i<nmain; i++){
    int s=__shfl(sv,i);
    float x=el[s]+erv; x=x>0.f?x:0.2f*x; x=__expf(x);
    unsigned short f=Fb[(size_t)s*40+l40];
    denom+=x; acc=fmaf(x,__uint_as_float(((uint32)f)<<16),acc);
  }
  if (deg > 64){
    for (int e=beg+64; e<end; e++){
      int s=csr_src[e];
      float x=el[s]+erv; x=x>0.f?x:0.2f*x; x=__expf(x);
      unsigned short f=Fb[(size_t)s*40+l40];
      denom+=x; acc=fmaf(x,__uint_as_float(((uint32)f)<<16),acc);
    }
  }
  float logit = acc/denom;
  float m = act ? logit : -INFINITY;
  for (int off=32; off; off>>=1) m = fmaxf(m, __shfl_xor(m, off));
  float ex = act ? expf(logit - m) : 0.f;
  float ssum = ex;
  for (int off=32; off; off>>=1) ssum += __shfl_xor(ssum, off);
  if (act) out[(size_t)node*40 + lane] = logit - m - logf(ssum);
}

extern "C" void kernel_launch(void* const* d_in, const int* in_sizes, int n_in,
                              void* d_out, int out_size, void* d_ws, size_t ws_size,
                              hipStream_t stream){
  const float* inputs = (const float*)d_in[0];
  const float* W0  = (const float*)d_in[1];
  const float* al0 = (const float*)d_in[2];
  const float* ar0 = (const float*)d_in[3];
  const float* W1  = (const float*)d_in[4];
  const float* al1 = (const float*)d_in[5];
  const float* ar1 = (const float*)d_in[6];
  const float* W2  = (const float*)d_in[7];
  const float* al2 = (const float*)d_in[8];
  const float* ar2 = (const float*)d_in[9];
  const int* src = (const int*)d_in[10];
  const int* dst = (const int*)d_in[11];
  int N = in_sizes[0]/128;
  int E = in_sizes[10];

  char* p = (char*)d_ws;
  auto carve = [&](size_t bytes)->char*{ char* q=p; p += ((bytes+255)/256)*256; return q; };
  unsigned short* Fb   = (unsigned short*)carve((size_t)N*128*2);  // bf16 feat
  unsigned short* Fb40 = (unsigned short*)carve((size_t)N*40*2);   // bf16 layer-2 feat
  float* bufH = (float*)carve((size_t)N*128*4);                    // fp32 hidden
  float* el  = (float*)carve((size_t)N*4*4);
  float* er  = (float*)carve((size_t)N*4*4);
  float* el2 = (float*)carve((size_t)N*4);
  float* er2 = (float*)carve((size_t)N*4);
  int* deg     = (int*)carve((size_t)N*4);
  int* row_ptr = (int*)carve((size_t)(N+1)*4);
  int* cursor  = (int*)carve((size_t)N*4);
  int* partials= (int*)carve(128*4);
  int* csr_src = (int*)carve((size_t)E*4);

  hipMemsetAsync(deg, 0, (size_t)N*4, stream);
  int nchunk = (N+1023)/1024;
  k_hist   <<<(E+255)/256, 256, 0, stream>>>(dst, deg, E);
  k_scanA  <<<nchunk, 256, 0, stream>>>(deg, partials, N);
  k_scanB  <<<1, 128, 0, stream>>>(partials, nchunk, row_ptr, N);
  k_scanC  <<<nchunk, 1024, 0, stream>>>(deg, partials, row_ptr, cursor, N);
  k_scatter<<<(E+255)/256, 256, 0, stream>>>(src, dst, cursor, csr_src, E);

  int gRows = (N+63)/64;
  int gWave = (N+3)/4;
  // layer 0
  k_gemm128<<<gRows,256,0,stream>>>(inputs, W0, al0, ar0, Fb, el, er, N);
  k_agg128 <<<gWave,256,0,stream>>>((const uint32*)Fb, el, er, row_ptr, csr_src, bufH, N);
  // layer 1
  k_gemm128<<<gRows,256,0,stream>>>(bufH, W1, al1, ar1, Fb, el, er, N);
  k_agg128 <<<gWave,256,0,stream>>>((const uint32*)Fb, el, er, row_ptr, csr_src, bufH, N);
  // layer 2
  k_gemm40 <<<gWave,256,0,stream>>>(bufH, W2, al2, ar2, Fb40, el2, er2, N);
  k_agg40  <<<gWave,256,0,stream>>>(Fb40, el2, er2, row_ptr, csr_src, (float*)d_out, N);
}